// Round 2
// baseline (473.610 us; speedup 1.0000x reference)
//
#include <hip/hip_runtime.h>
#include <math.h>

#define D 2048
#define D4 512               // float4 per row
#define M 32
#define ROWS 8
#define SCALE 0.022097086912079608f  // 1/sqrt(2048)

// ws layout (floats):
//   [0      , 65536)  WqmT[m][d] = SCALE * sum_e mem[m][e]*Wq[e][d]   (atomics, memset'd)
//   [65536  , 131072) Wm2 [m][e] = sum_d mem[m][d]*Wm[e][d]           (direct store)
//   [131072 , 131104) cq  [m]    = SCALE * sum_e bq[e]*mem[m][e]      (direct store)

#define GLOAD_LDS16(g, l) __builtin_amdgcn_global_load_lds( \
    (const __attribute__((address_space(1))) void*)(g),     \
    (__attribute__((address_space(3))) void*)(l), 16, 0, 0)

// ---------------- single precompute kernel ----------------
__global__ __launch_bounds__(256) void k_pre(const float* __restrict__ Wq,
                                             const float* __restrict__ Wm,
                                             const float* __restrict__ mem,
                                             const float* __restrict__ bq,
                                             float* __restrict__ WqmT,
                                             float* __restrict__ Wm2,
                                             float* __restrict__ cqs) {
    __shared__ float memL[M * 256];   // 32 KB (part B only)
    const int t = threadIdx.x;
    const int w = t >> 6, lane = t & 63;

    if (blockIdx.x < 64) {
        // part A: WqmT[m][d] = SCALE * sum_e mem[m][e] * Wq[e][d]
        // wave unit: (d-chunk of 128) x (e-chunk of 128); 256 units = 64 blocks
        const int unit = blockIdx.x * 4 + w;
        const int dc = unit & 15;
        const int es = unit >> 4;
        const int dl = dc * 64 + lane;            // float2 column index
        const float2* Wq2 = (const float2*)Wq;
        float2 acc[M];
#pragma unroll
        for (int m = 0; m < M; ++m) acc[m] = make_float2(0.f, 0.f);
        const int e0 = es * 128;
        for (int e = e0; e < e0 + 128; ++e) {
            float2 wv = Wq2[(size_t)e * (D / 2) + dl];   // coalesced, streams Wq once
#pragma unroll
            for (int m = 0; m < M; ++m) {
                float s = mem[m * D + e];                 // wave-uniform -> scalar load
                acc[m].x = fmaf(s, wv.x, acc[m].x);
                acc[m].y = fmaf(s, wv.y, acc[m].y);
            }
        }
#pragma unroll
        for (int m = 0; m < M; ++m) {
            atomicAdd(&WqmT[m * D + 2 * dl],     acc[m].x * SCALE);
            atomicAdd(&WqmT[m * D + 2 * dl + 1], acc[m].y * SCALE);
        }
    } else {
        // part B: wave per output row e: Wm2[m][e] = dot(mem[m], Wm[e]); e==2048 -> cq from bq
        const int e = (blockIdx.x - 64) * 4 + w;          // 0..2051
        const bool active = (e < D + 1);
        const float4* W4 = (const float4*)((e < D) ? (Wm + (size_t)e * D) : bq);
        const float4* mem4 = (const float4*)mem;
        float a[M];
#pragma unroll
        for (int m = 0; m < M; ++m) a[m] = 0.f;
        for (int c = 0; c < 8; ++c) {
            // stage mem[:, c*256 .. +256) = 32 KB, coalesced
#pragma unroll
            for (int q = 0; q < 8; ++q) {
                int i4 = t + 256 * q;                     // 0..2047
                int m = i4 >> 6, k = i4 & 63;
                ((float4*)memL)[i4] = mem4[m * D4 + c * 64 + k];
            }
            __syncthreads();
            if (active) {
                float4 wr = W4[c * 64 + lane];
#pragma unroll
                for (int m = 0; m < M; ++m) {
                    float4 mv = ((const float4*)memL)[m * 64 + lane];
                    a[m] = fmaf(wr.x, mv.x, fmaf(wr.y, mv.y,
                           fmaf(wr.z, mv.z, fmaf(wr.w, mv.w, a[m]))));
                }
            }
            __syncthreads();
        }
        // split-tree reduce: 32 accs over 64 lanes (37 shuffles total)
#pragma unroll
        for (int s = 0; s < 5; ++s) {
            const int msk = 1 << s;
            const int bit = (lane >> s) & 1;
            const int n = 32 >> s;
#pragma unroll
            for (int i = 0; i < n / 2; ++i) {
                float send = bit ? a[2 * i] : a[2 * i + 1];
                float recv = __shfl_xor(send, msk, 64);
                a[i] = (bit ? a[2 * i + 1] : a[2 * i]) + recv;
            }
        }
        float tot = a[0] + __shfl_xor(a[0], 32, 64);      // lane l holds m = l&31
        if (active && lane < 32) {
            if (e < D) Wm2[lane * D + e] = tot;
            else       cqs[lane] = tot * SCALE;
        }
    }
}

// ---------------- fused main ----------------
__global__ __launch_bounds__(512, 2) void k_main(const float* __restrict__ x,
                                                 const float* __restrict__ WqmT,
                                                 const float* __restrict__ Wm2,
                                                 const float* __restrict__ cqs,
                                                 const float* __restrict__ bm,
                                                 float* __restrict__ out) {
    __shared__ float xs[ROWS * D];          // 64 KB: 8 rows of x
    __shared__ float attnL[ROWS * M];       // 1 KB
    __shared__ float4 wT[M * 2];            // softmax weights, [m][r] transposed
    const int t = threadIdx.x;
    const int w = t >> 6, lane = t & 63;
    const long row0 = (long)blockIdx.x * ROWS;
    const float* xg = x + row0 * D;

    // async global->LDS staging of x (8 KB per wave, linear dest)
#pragma unroll
    for (int i = 0; i < 8; ++i) {
        const int off = w * 2048 + i * 256;
        GLOAD_LDS16(xg + off + lane * 4, xs + off);
    }

    // phase A: wave w owns m in [4w, 4w+4); acc idx = j*8 + r
    float a[M];
#pragma unroll
    for (int i = 0; i < M; ++i) a[i] = 0.f;
    const float4* xs4 = (const float4*)xs;
    const float4* Wg4 = (const float4*)WqmT + (size_t)(4 * w) * D4;

    __syncthreads();   // drains vmcnt -> x staged

#pragma unroll
    for (int c = 0; c < 8; ++c) {
        float4 wq[4];
#pragma unroll
        for (int j = 0; j < 4; ++j) wq[j] = Wg4[j * D4 + c * 64 + lane];   // L2-resident
#pragma unroll
        for (int r = 0; r < ROWS; ++r) {
            float4 xv = xs4[r * D4 + c * 64 + lane];
#pragma unroll
            for (int j = 0; j < 4; ++j) {
                a[j * 8 + r] = fmaf(wq[j].x, xv.x, fmaf(wq[j].y, xv.y,
                               fmaf(wq[j].z, xv.z, fmaf(wq[j].w, xv.w, a[j * 8 + r]))));
            }
        }
    }
    // split-tree reduce 32 accs over 64 lanes
#pragma unroll
    for (int s = 0; s < 5; ++s) {
        const int msk = 1 << s;
        const int bit = (lane >> s) & 1;
        const int n = 32 >> s;
#pragma unroll
        for (int i = 0; i < n / 2; ++i) {
            float send = bit ? a[2 * i] : a[2 * i + 1];
            float recv = __shfl_xor(send, msk, 64);
            a[i] = (bit ? a[2 * i + 1] : a[2 * i]) + recv;
        }
    }
    float tot = a[0] + __shfl_xor(a[0], 32, 64);   // idx = lane&31 : j=(lane>>3)&3, r=lane&7
    {
        const int j = (lane >> 3) & 3, r = lane & 7;
        const int m = 4 * w + j;
        if (lane < 32) attnL[r * M + m] = tot + cqs[m];
    }
    __syncthreads();

    // softmax over m (first 4 waves; half-wave per row)
    if (t < 256) {
        const int r = t >> 5, m = t & 31;
        float v = attnL[r * M + m];
        float mx = v;
#pragma unroll
        for (int s2 = 1; s2 < 32; s2 <<= 1) mx = fmaxf(mx, __shfl_xor(mx, s2, 32));
        float e = expf(v - mx);
        float sum = e;
#pragma unroll
        for (int s2 = 1; s2 < 32; s2 <<= 1) sum += __shfl_xor(sum, s2, 32);
        ((float*)wT)[m * ROWS + r] = e / sum;
    }
    __syncthreads();

    // phase B: wave w owns 256-float d-slice; out = x + bm + w @ Wm2
    const int base = w * 64 + lane;                 // float4 column
    const float4* W2 = (const float4*)Wm2;
    const float4 bv = ((const float4*)bm)[base];
    float4 o[ROWS];
#pragma unroll
    for (int r = 0; r < ROWS; ++r) {
        float4 xv = xs4[r * D4 + base];
        o[r] = make_float4(xv.x + bv.x, xv.y + bv.y, xv.z + bv.z, xv.w + bv.w);
    }
#pragma unroll
    for (int m = 0; m < M; ++m) {
        float4 wv = W2[(size_t)m * D4 + base];      // L2-resident, coalesced
        float4 wa = wT[m * 2];                      // uniform LDS broadcast: w[m][0..3]
        float4 wb = wT[m * 2 + 1];                  // w[m][4..7]
        const float wr[8] = {wa.x, wa.y, wa.z, wa.w, wb.x, wb.y, wb.z, wb.w};
#pragma unroll
        for (int r = 0; r < ROWS; ++r) {
            o[r].x = fmaf(wr[r], wv.x, o[r].x);
            o[r].y = fmaf(wr[r], wv.y, o[r].y);
            o[r].z = fmaf(wr[r], wv.z, o[r].z);
            o[r].w = fmaf(wr[r], wv.w, o[r].w);
        }
    }
    float4* og = (float4*)(out + row0 * D);
#pragma unroll
    for (int r = 0; r < ROWS; ++r) og[r * D4 + base] = o[r];
}

extern "C" void kernel_launch(void* const* d_in, const int* in_sizes, int n_in,
                              void* d_out, int out_size, void* d_ws, size_t ws_size,
                              hipStream_t stream) {
    const float* x   = (const float*)d_in[0];
    const float* mem = (const float*)d_in[1];
    const float* Wq  = (const float*)d_in[2];
    const float* bq  = (const float*)d_in[3];
    const float* Wm  = (const float*)d_in[4];
    const float* bm  = (const float*)d_in[5];
    float* out = (float*)d_out;

    const size_t need = (size_t)(2 * M * D + M) * sizeof(float);
    if (ws_size < need) return;

    float* WqmT = (float*)d_ws;
    float* Wm2  = WqmT + M * D;
    float* cq   = Wm2 + M * D;

    // zero only the atomically-accumulated panel (ws is re-poisoned each launch)
    hipMemsetAsync(WqmT, 0, (size_t)(M * D) * sizeof(float), stream);

    k_pre <<<64 + 513, 256, 0, stream>>>(Wq, Wm, mem, bq, WqmT, Wm2, cq);
    k_main<<<2048, 512, 0, stream>>>(x, WqmT, Wm2, cq, bm, out);
}